// Round 2
// baseline (1951.084 us; speedup 1.0000x reference)
//
#include <hip/hip_runtime.h>
#include <stdint.h>
#include <stddef.h>

// S=8192, D=1024 causal attention + QKV proj.
// cast->bf16, fused QKV MFMA GEMM, V transpose, flash attention (Br=64, 8 waves,
// parity split-K over key tiles, async LDS ring staging), merge kernel.

#define SEQ   8192
#define DIM   1024

typedef __bf16 bf16x8 __attribute__((ext_vector_type(8)));
typedef float  f32x4  __attribute__((ext_vector_type(4)));
typedef uint16_t u16x8 __attribute__((ext_vector_type(8)));

#define MFMA16(a, b, c) __builtin_amdgcn_mfma_f32_16x16x32_bf16((a), (b), (c), 0, 0, 0)

__device__ __forceinline__ uint16_t f2bf(float f) {
  uint32_t u = __builtin_bit_cast(uint32_t, f);
  return (uint16_t)((u + 0x7fffu + ((u >> 16) & 1u)) >> 16);
}
__device__ __forceinline__ float bf2f(uint16_t h) {
  uint32_t u = ((uint32_t)h) << 16;
  return __builtin_bit_cast(float, u);
}

typedef const __attribute__((address_space(1))) uint32_t* gas_t;
typedef __attribute__((address_space(3))) uint32_t* las_t;
__device__ __forceinline__ void async16(const void* g, void* l) {
  // 16B per lane; LDS dest = wave-uniform base + lane*16 (m97/m104 semantics)
  __builtin_amdgcn_global_load_lds((gas_t)g, (las_t)l, 16, 0, 0);
}

// ---------------------------------------------------------------- cast kernel
__global__ __launch_bounds__(256) void cast_f32_bf16(const float* __restrict__ src,
                                                     uint16_t* __restrict__ dst, int n) {
  int i = (blockIdx.x * 256 + threadIdx.x) * 4;
  if (i + 3 < n) {
    float4 v = *(const float4*)(src + i);
    ushort4 o;
    o.x = f2bf(v.x); o.y = f2bf(v.y); o.z = f2bf(v.z); o.w = f2bf(v.w);
    *(ushort4*)(dst + i) = o;
  }
}

// ------------------------------------------------------------- QKV GEMM (unchanged, known-good)
__global__ __launch_bounds__(256) void qkv_gemm(const uint16_t* __restrict__ A,
                                                const uint16_t* __restrict__ B,
                                                uint16_t* __restrict__ Qb,
                                                uint16_t* __restrict__ Kb,
                                                uint16_t* __restrict__ Vb) {
  __shared__ __align__(16) uint16_t As[128][72];
  __shared__ __align__(16) uint16_t Bs[128][72];
  const int t    = threadIdx.x;
  const int w    = t >> 6;
  const int lane = t & 63;
  const int lm   = lane & 15;
  const int qd   = lane >> 4;
  const int wrow = (w >> 1) * 64;
  const int wcol = (w & 1) * 64;
  const int rowbase = blockIdx.y * 128;
  const int colbase = blockIdx.x * 128;

  f32x4 acc[4][4] = {};

  for (int kb = 0; kb < DIM; kb += 64) {
    __syncthreads();
#pragma unroll
    for (int rep = 0; rep < 4; ++rep) {
      int i = rep * 256 + t;
      int r = i >> 3, c8 = i & 7;
      *(uint4*)(&As[r][c8 * 8]) =
          *(const uint4*)(A + (size_t)(rowbase + r) * DIM + kb + c8 * 8);
    }
#pragma unroll
    for (int rep = 0; rep < 4; ++rep) {
      int i = rep * 256 + t;
      int r = i >> 3, c8 = i & 7;
      *(uint4*)(&Bs[r][c8 * 8]) =
          *(const uint4*)(B + (size_t)(colbase + r) * DIM + kb + c8 * 8);
    }
    __syncthreads();
#pragma unroll
    for (int kc = 0; kc < 2; ++kc) {
      bf16x8 af[4], bfr[4];
#pragma unroll
      for (int mt = 0; mt < 4; ++mt)
        af[mt] = *(const bf16x8*)(&As[wrow + mt * 16 + lm][kc * 32 + qd * 8]);
#pragma unroll
      for (int nt = 0; nt < 4; ++nt)
        bfr[nt] = *(const bf16x8*)(&Bs[wcol + nt * 16 + lm][kc * 32 + qd * 8]);
#pragma unroll
      for (int mt = 0; mt < 4; ++mt)
#pragma unroll
        for (int nt = 0; nt < 4; ++nt)
          acc[mt][nt] = MFMA16(af[mt], bfr[nt], acc[mt][nt]);
    }
  }

#pragma unroll
  for (int mt = 0; mt < 4; ++mt)
#pragma unroll
    for (int nt = 0; nt < 4; ++nt)
#pragma unroll
      for (int r = 0; r < 4; ++r) {
        int m = rowbase + wrow + mt * 16 + qd * 4 + r;
        int n = colbase + wcol + nt * 16 + lm;
        uint16_t v = f2bf(acc[mt][nt][r]);
        if (n < 1024)       Qb[(size_t)m * DIM + n]          = v;
        else if (n < 2048)  Kb[(size_t)m * DIM + (n - 1024)] = v;
        else                Vb[(size_t)m * DIM + (n - 2048)] = v;
      }
}

// ------------------------------------------------------------ V transpose (unchanged)
__global__ __launch_bounds__(256) void transpose_v(const uint16_t* __restrict__ Vb,
                                                   uint16_t* __restrict__ Vt) {
  __shared__ __align__(16) uint16_t tile[64][72];
  const int t  = threadIdx.x;
  const int mb = blockIdx.x * 64;
  const int db = blockIdx.y * 64;
#pragma unroll
  for (int rep = 0; rep < 2; ++rep) {
    int i = rep * 256 + t;
    int r = i >> 3, c = (i & 7) * 8;
    *(uint4*)(&tile[r][c]) = *(const uint4*)(Vb + (size_t)(mb + r) * DIM + db + c);
  }
  __syncthreads();
#pragma unroll
  for (int rep = 0; rep < 2; ++rep) {
    int i = rep * 256 + t;
    int d = i >> 3, mq = (i & 7) * 8;
    u16x8 v;
#pragma unroll
    for (int u = 0; u < 8; ++u) v[u] = tile[mq + u][d];
    *(u16x8*)(Vt + (size_t)(db + d) * SEQ + mb + mq) = v;
  }
}

// ------------------------------------------------------------ flash attention
// Br=64 rows/block, Bc=128 keys/iter, 8 waves (512 thr).
// grid=256: block b -> (tile tt = 127-(b>>1), parity = b&1); processes key tiles
// jg = par, par+2, ... < jn. Writes UNNORMALIZED partial O (bf16) + m,l per row.
// K and V stream through a shared 2x32KB LDS ring via global_load_lds with an
// XOR-16B-group swizzle (unpadded rows, conflict-free <=2-way reads).
__global__ __launch_bounds__(512, 2) void attn_kernel(const uint16_t* __restrict__ Qb,
                                                      const uint16_t* __restrict__ Kb,
                                                      const uint16_t* __restrict__ Vt,
                                                      uint16_t* __restrict__ P0,
                                                      uint16_t* __restrict__ P1,
                                                      float* __restrict__ Mm,
                                                      float* __restrict__ Ll) {
  __shared__ __align__(16) uint8_t ring[2][32768];  // K chunk: 16KB, V chunk: 32KB
  __shared__ float S[64][132];
  __shared__ __align__(16) uint16_t P[64][136];
  __shared__ float alpha_s[64];

  const int t    = threadIdx.x;
  const int w    = t >> 6;
  const int lane = t & 63;
  const int lm   = lane & 15;
  const int qd   = lane >> 4;
  const int wr   = w >> 2;   // phase-A row group (0/1)
  const int wc   = w & 3;    // phase-A col group (0..3)

  const int par  = blockIdx.x & 1;
  const int tt   = 127 - (blockIdx.x >> 1);   // longest tiles first
  const int row0 = tt * 64;
  const int jn   = tt / 2 + 1;                // # of 128-key tiles for this row tile

  const int kx = (lane & 7) ^ ((lane >> 3) & 7);  // K-loader global 16B-group

  float m_run = -1e30f, l_run = 0.0f;
  f32x4 o_acc[4][8] = {};
  const float c1 = 0.045084220027780106f;  // log2(e) / sqrt(1024)

  const int srow  = t >> 3;
  const int scol0 = (t & 7) * 16;

  // prologue: stage K chunk0 of first j
  if (par < jn) {
#pragma unroll
    for (int i = 0; i < 2; ++i) {
      int R = w * 16 + i * 8 + (lane >> 3);
      async16(Kb + (size_t)(par * 128 + R) * DIM + kx * 8,
              &ring[0][(w * 16 + i * 8) * 128]);
    }
  }
  __syncthreads();

#pragma unroll 1
  for (int jg = par; jg < jn; jg += 2) {
    // ---- Phase A: S[64,128] = Q K^T over 16 chunks of BK=64 -------------
    f32x4 sacc[2][2] = {};
    // Q frags for chunk 0 (prefetched one chunk ahead thereafter)
    bf16x8 qc[2][2], qn[2][2];
#pragma unroll
    for (int mt = 0; mt < 2; ++mt)
#pragma unroll
      for (int kc = 0; kc < 2; ++kc)
        qc[mt][kc] = *(const bf16x8*)(Qb + (size_t)(row0 + wr * 32 + mt * 16 + lm) * DIM
                                      + kc * 32 + qd * 8);
#pragma unroll 1
    for (int c = 0; c < 16; ++c) {
      if (c < 15) {
        // issue K chunk c+1
        int cc = c + 1;
#pragma unroll
        for (int i = 0; i < 2; ++i) {
          int R = w * 16 + i * 8 + (lane >> 3);
          async16(Kb + (size_t)(jg * 128 + R) * DIM + cc * 64 + kx * 8,
                  &ring[cc & 1][(w * 16 + i * 8) * 128]);
        }
        // prefetch Q chunk c+1
#pragma unroll
        for (int mt = 0; mt < 2; ++mt)
#pragma unroll
          for (int kc = 0; kc < 2; ++kc)
            qn[mt][kc] = *(const bf16x8*)(Qb + (size_t)(row0 + wr * 32 + mt * 16 + lm) * DIM
                                          + cc * 64 + kc * 32 + qd * 8);
      } else {
        // issue V chunk 0 (for this j's phase C)
#pragma unroll
        for (int i = 0; i < 4; ++i) {
          int r  = i * 4 + (lane >> 4);
          int gx = (lane & 15) ^ (r & 7);
          async16(Vt + (size_t)(w * 128 + r) * SEQ + jg * 128 + gx * 8,
                  &ring[0][w * 4096 + i * 1024]);
        }
      }
      // compute chunk c from ring[c&1]
      bf16x8 bfr[2][2];
#pragma unroll
      for (int kc = 0; kc < 2; ++kc)
#pragma unroll
        for (int nt = 0; nt < 2; ++nt) {
          int R  = wc * 32 + nt * 16 + lm;
          int gs = (kc * 4 + qd) ^ (lm & 7);
          bfr[nt][kc] = *(const bf16x8*)&ring[c & 1][R * 128 + gs * 16];
        }
#pragma unroll
      for (int kc = 0; kc < 2; ++kc)
#pragma unroll
        for (int mt = 0; mt < 2; ++mt)
#pragma unroll
          for (int nt = 0; nt < 2; ++nt)
            sacc[mt][nt] = MFMA16(qc[mt][kc], bfr[nt][kc], sacc[mt][nt]);
      __syncthreads();  // drains DMA c+1 / V c0 (+ q prefetch)
#pragma unroll
      for (int mt = 0; mt < 2; ++mt)
#pragma unroll
        for (int kc = 0; kc < 2; ++kc)
          qc[mt][kc] = qn[mt][kc];
    }
    // write S
#pragma unroll
    for (int mt = 0; mt < 2; ++mt)
#pragma unroll
      for (int nt = 0; nt < 2; ++nt)
#pragma unroll
        for (int r = 0; r < 4; ++r)
          S[wr * 32 + mt * 16 + qd * 4 + r][wc * 32 + nt * 16 + lm] = sacc[mt][nt][r];
    __syncthreads();

    // ---- Phase B: online softmax (8 threads per row) --------------------
    const bool maskt = (jg == jn - 1);
    float sv[16];
    float mx = -1e30f;
#pragma unroll
    for (int cc = 0; cc < 16; ++cc) {
      float s = S[srow][scol0 + cc];
      if (maskt && (jg * 128 + scol0 + cc > row0 + srow)) s = -1e30f;
      sv[cc] = s;
      mx = fmaxf(mx, s);
    }
    mx = fmaxf(mx, __shfl_xor(mx, 1, 8));
    mx = fmaxf(mx, __shfl_xor(mx, 2, 8));
    mx = fmaxf(mx, __shfl_xor(mx, 4, 8));
    float mn    = fmaxf(m_run, mx);
    float alpha = exp2f((m_run - mn) * c1);
    float psum  = 0.0f;
#pragma unroll
    for (int cc = 0; cc < 16; ++cc) {
      float p = exp2f((sv[cc] - mn) * c1);
      psum += p;
      P[srow][scol0 + cc] = f2bf(p);
    }
    psum += __shfl_xor(psum, 1, 8);
    psum += __shfl_xor(psum, 2, 8);
    psum += __shfl_xor(psum, 4, 8);
    l_run = alpha * l_run + psum;
    m_run = mn;
    if ((t & 7) == 0) alpha_s[srow] = alpha;
    __syncthreads();

    // ---- Phase C: O = alpha*O + P @ V; wave w owns d-slice [128w,128w+128)
    float al[4][4];
#pragma unroll
    for (int mt = 0; mt < 4; ++mt)
#pragma unroll
      for (int r = 0; r < 4; ++r)
        al[mt][r] = alpha_s[mt * 16 + qd * 4 + r];
#pragma unroll
    for (int mt = 0; mt < 4; ++mt)
#pragma unroll
      for (int c = 0; c < 8; ++c)
#pragma unroll
        for (int r = 0; r < 4; ++r)
          o_acc[mt][c][r] *= al[mt][r];
    bf16x8 pf[4][4];
#pragma unroll
    for (int mt = 0; mt < 4; ++mt)
#pragma unroll
      for (int kc = 0; kc < 4; ++kc)
        pf[mt][kc] = *(const bf16x8*)(&P[mt * 16 + lm][kc * 32 + qd * 8]);

#pragma unroll 1
    for (int c = 0; c < 8; ++c) {
      if (c < 7) {
        // issue V chunk c+1
        int cc = c + 1;
#pragma unroll
        for (int i = 0; i < 4; ++i) {
          int r  = i * 4 + (lane >> 4);
          int gx = (lane & 15) ^ (r & 7);
          async16(Vt + (size_t)(w * 128 + cc * 16 + r) * SEQ + jg * 128 + gx * 8,
                  &ring[cc & 1][w * 4096 + i * 1024]);
        }
      } else if (jg + 2 < jn) {
        // issue K chunk 0 of next j
#pragma unroll
        for (int i = 0; i < 2; ++i) {
          int R = w * 16 + i * 8 + (lane >> 3);
          async16(Kb + (size_t)((jg + 2) * 128 + R) * DIM + kx * 8,
                  &ring[0][(w * 16 + i * 8) * 128]);
        }
      }
      // compute chunk c (16 d-values per wave) from ring[c&1]
#pragma unroll
      for (int kc = 0; kc < 4; ++kc) {
        int gs = (kc * 4 + qd) ^ (lm & 7);
        bf16x8 vf = *(const bf16x8*)&ring[c & 1][w * 4096 + lm * 256 + gs * 16];
#pragma unroll
        for (int mt = 0; mt < 4; ++mt)
          o_acc[mt][c] = MFMA16(pf[mt][kc], vf, o_acc[mt][c]);
      }
      __syncthreads();
    }
  }

  // ---- epilogue: write unnormalized partial O (bf16) + m,l --------------
  uint16_t* Pp = par ? P1 : P0;
#pragma unroll
  for (int mt = 0; mt < 4; ++mt)
#pragma unroll
    for (int c = 0; c < 8; ++c)
#pragma unroll
      for (int r = 0; r < 4; ++r) {
        int row = row0 + mt * 16 + qd * 4 + r;
        int d   = w * 128 + c * 16 + lm;
        Pp[(size_t)row * DIM + d] = f2bf(o_acc[mt][c][r]);
      }
  if ((t & 7) == 0) {
    Mm[par * SEQ + row0 + srow] = m_run;
    Ll[par * SEQ + row0 + srow] = l_run;
  }
}

// ------------------------------------------------------------ merge partials
__global__ __launch_bounds__(256) void merge_kernel(const uint16_t* __restrict__ P0,
                                                    const uint16_t* __restrict__ P1,
                                                    const float* __restrict__ Mm,
                                                    const float* __restrict__ Ll,
                                                    float* __restrict__ out) {
  const int row = blockIdx.x;
  const int d0  = threadIdx.x * 4;
  const float c1 = 0.045084220027780106f;
  float m0 = Mm[row], m1 = Mm[SEQ + row];
  float l0 = Ll[row], l1 = Ll[SEQ + row];
  float m  = fmaxf(m0, m1);
  float a0 = exp2f((m0 - m) * c1);
  float a1 = exp2f((m1 - m) * c1);
  float inv = 1.0f / (a0 * l0 + a1 * l1);
  ushort4 p0 = *(const ushort4*)(P0 + (size_t)row * DIM + d0);
  ushort4 p1 = *(const ushort4*)(P1 + (size_t)row * DIM + d0);
  float4 o;
  o.x = (a0 * bf2f(p0.x) + a1 * bf2f(p1.x)) * inv;
  o.y = (a0 * bf2f(p0.y) + a1 * bf2f(p1.y)) * inv;
  o.z = (a0 * bf2f(p0.z) + a1 * bf2f(p1.z)) * inv;
  o.w = (a0 * bf2f(p0.w) + a1 * bf2f(p1.w)) * inv;
  *(float4*)(out + (size_t)row * DIM + d0) = o;
}

// ---------------------------------------------------------------- launch
extern "C" void kernel_launch(void* const* d_in, const int* in_sizes, int n_in,
                              void* d_out, int out_size, void* d_ws, size_t ws_size,
                              hipStream_t stream) {
  (void)in_sizes; (void)n_in; (void)out_size; (void)ws_size;
  const float* x  = (const float*)d_in[0];
  const float* wq = (const float*)d_in[1];
  const float* wk = (const float*)d_in[2];
  const float* wv = (const float*)d_in[3];
  float* out = (float*)d_out;

  char* ws = (char*)d_ws;
  // layout (MB): Qb[0,16) Kb[16,32) Vt[32,48) Vb[48,64) xb[64,80) wcat[80,86.3)
  // after GEMM/transpose: P0 over Vb, P1 over xb, Mm/Ll over wcat.
  uint16_t* Qb   = (uint16_t*)(ws);
  uint16_t* Kb   = (uint16_t*)(ws + 16777216);
  uint16_t* Vt   = (uint16_t*)(ws + 33554432);
  uint16_t* Vb   = (uint16_t*)(ws + 50331648);
  uint16_t* P0   = (uint16_t*)(ws + 50331648);   // aliases Vb (dead after transpose)
  uint16_t* xb   = (uint16_t*)(ws + 67108864);
  uint16_t* P1   = (uint16_t*)(ws + 67108864);   // aliases xb (dead after GEMM)
  uint16_t* wcat = (uint16_t*)(ws + 83886080);
  float*    Mm   = (float*)(ws + 83886080);      // aliases wcat (dead after GEMM)
  float*    Ll   = (float*)(ws + 83886080 + 65536);

  cast_f32_bf16<<<8192, 256, 0, stream>>>(x,  xb,                   SEQ * DIM);
  cast_f32_bf16<<<1024, 256, 0, stream>>>(wq, wcat,                 DIM * DIM);
  cast_f32_bf16<<<1024, 256, 0, stream>>>(wk, wcat + DIM * DIM,     DIM * DIM);
  cast_f32_bf16<<<1024, 256, 0, stream>>>(wv, wcat + 2 * DIM * DIM, DIM * DIM);

  qkv_gemm<<<dim3(24, 64), 256, 0, stream>>>(xb, wcat, Qb, Kb, Vb);
  transpose_v<<<dim3(SEQ / 64, DIM / 64), 256, 0, stream>>>(Vb, Vt);
  attn_kernel<<<256, 512, 0, stream>>>(Qb, Kb, Vt, P0, P1, Mm, Ll);
  merge_kernel<<<SEQ, 256, 0, stream>>>(P0, P1, Mm, Ll, out);
}

// Round 3
// 1445.828 us; speedup vs baseline: 1.3495x; 1.3495x over previous
//
#include <hip/hip_runtime.h>
#include <stdint.h>
#include <stddef.h>

// S=8192, D=1024 causal attention + QKV proj.
// cast->bf16, fused QKV MFMA GEMM, V transpose, flash attention (Br=64, 8 waves,
// parity split over key tiles, register softmax, direct global K/V), merge.

#define SEQ   8192
#define DIM   1024

typedef __bf16 bf16x8 __attribute__((ext_vector_type(8)));
typedef float  f32x4  __attribute__((ext_vector_type(4)));
typedef uint16_t u16x8 __attribute__((ext_vector_type(8)));

#define MFMA16(a, b, c) __builtin_amdgcn_mfma_f32_16x16x32_bf16((a), (b), (c), 0, 0, 0)

__device__ __forceinline__ uint16_t f2bf(float f) {
  uint32_t u = __builtin_bit_cast(uint32_t, f);
  return (uint16_t)((u + 0x7fffu + ((u >> 16) & 1u)) >> 16);
}
__device__ __forceinline__ float bf2f(uint16_t h) {
  uint32_t u = ((uint32_t)h) << 16;
  return __builtin_bit_cast(float, u);
}

// ---------------------------------------------------------------- cast kernel
__global__ __launch_bounds__(256) void cast_f32_bf16(const float* __restrict__ src,
                                                     uint16_t* __restrict__ dst, int n) {
  int i = (blockIdx.x * 256 + threadIdx.x) * 4;
  if (i + 3 < n) {
    float4 v = *(const float4*)(src + i);
    ushort4 o;
    o.x = f2bf(v.x); o.y = f2bf(v.y); o.z = f2bf(v.z); o.w = f2bf(v.w);
    *(ushort4*)(dst + i) = o;
  }
}

// ------------------------------------------------------------- QKV GEMM (known-good)
__global__ __launch_bounds__(256) void qkv_gemm(const uint16_t* __restrict__ A,
                                                const uint16_t* __restrict__ B,
                                                uint16_t* __restrict__ Qb,
                                                uint16_t* __restrict__ Kb,
                                                uint16_t* __restrict__ Vb) {
  __shared__ __align__(16) uint16_t As[128][72];
  __shared__ __align__(16) uint16_t Bs[128][72];
  const int t    = threadIdx.x;
  const int w    = t >> 6;
  const int lane = t & 63;
  const int lm   = lane & 15;
  const int qd   = lane >> 4;
  const int wrow = (w >> 1) * 64;
  const int wcol = (w & 1) * 64;
  const int rowbase = blockIdx.y * 128;
  const int colbase = blockIdx.x * 128;

  f32x4 acc[4][4] = {};

  for (int kb = 0; kb < DIM; kb += 64) {
    __syncthreads();
#pragma unroll
    for (int rep = 0; rep < 4; ++rep) {
      int i = rep * 256 + t;
      int r = i >> 3, c8 = i & 7;
      *(uint4*)(&As[r][c8 * 8]) =
          *(const uint4*)(A + (size_t)(rowbase + r) * DIM + kb + c8 * 8);
    }
#pragma unroll
    for (int rep = 0; rep < 4; ++rep) {
      int i = rep * 256 + t;
      int r = i >> 3, c8 = i & 7;
      *(uint4*)(&Bs[r][c8 * 8]) =
          *(const uint4*)(B + (size_t)(colbase + r) * DIM + kb + c8 * 8);
    }
    __syncthreads();
#pragma unroll
    for (int kc = 0; kc < 2; ++kc) {
      bf16x8 af[4], bfr[4];
#pragma unroll
      for (int mt = 0; mt < 4; ++mt)
        af[mt] = *(const bf16x8*)(&As[wrow + mt * 16 + lm][kc * 32 + qd * 8]);
#pragma unroll
      for (int nt = 0; nt < 4; ++nt)
        bfr[nt] = *(const bf16x8*)(&Bs[wcol + nt * 16 + lm][kc * 32 + qd * 8]);
#pragma unroll
      for (int mt = 0; mt < 4; ++mt)
#pragma unroll
        for (int nt = 0; nt < 4; ++nt)
          acc[mt][nt] = MFMA16(af[mt], bfr[nt], acc[mt][nt]);
    }
  }

#pragma unroll
  for (int mt = 0; mt < 4; ++mt)
#pragma unroll
    for (int nt = 0; nt < 4; ++nt)
#pragma unroll
      for (int r = 0; r < 4; ++r) {
        int m = rowbase + wrow + mt * 16 + qd * 4 + r;
        int n = colbase + wcol + nt * 16 + lm;
        uint16_t v = f2bf(acc[mt][nt][r]);
        if (n < 1024)       Qb[(size_t)m * DIM + n]          = v;
        else if (n < 2048)  Kb[(size_t)m * DIM + (n - 1024)] = v;
        else                Vb[(size_t)m * DIM + (n - 2048)] = v;
      }
}

// ------------------------------------------------------------ V transpose (known-good)
__global__ __launch_bounds__(256) void transpose_v(const uint16_t* __restrict__ Vb,
                                                   uint16_t* __restrict__ Vt) {
  __shared__ __align__(16) uint16_t tile[64][72];
  const int t  = threadIdx.x;
  const int mb = blockIdx.x * 64;
  const int db = blockIdx.y * 64;
#pragma unroll
  for (int rep = 0; rep < 2; ++rep) {
    int i = rep * 256 + t;
    int r = i >> 3, c = (i & 7) * 8;
    *(uint4*)(&tile[r][c]) = *(const uint4*)(Vb + (size_t)(mb + r) * DIM + db + c);
  }
  __syncthreads();
#pragma unroll
  for (int rep = 0; rep < 2; ++rep) {
    int i = rep * 256 + t;
    int d = i >> 3, mq = (i & 7) * 8;
    u16x8 v;
#pragma unroll
    for (int u = 0; u < 8; ++u) v[u] = tile[mq + u][d];
    *(u16x8*)(Vt + (size_t)(db + d) * SEQ + mb + mq) = v;
  }
}

// ------------------------------------------------------------ flash attention
// Br=64 rows/block, Bc=128 keys/iter, 8 waves (512 thr), parity split-2.
// grid=256: block b -> (tile tt = 127-(b>>1), parity = b&1); jg = par, par+2, ...
// Phase A: 2x4 wave grid (2 row-groups x 4 col-groups), Q/K direct from global.
// Softmax fully in C-layout registers; cross-wave row stats via 1KB LDS buffer.
// Phase C: wave w owns d-slice [128w,128w+128); P via LDS (A-layout transpose),
// V direct from global Vt (k-major). Writes unnormalized partial O + (m,l).
__global__ __launch_bounds__(512, 2) void attn_kernel(const uint16_t* __restrict__ Qb,
                                                      const uint16_t* __restrict__ Kb,
                                                      const uint16_t* __restrict__ Vt,
                                                      uint16_t* __restrict__ P0,
                                                      uint16_t* __restrict__ P1,
                                                      float* __restrict__ Mm,
                                                      float* __restrict__ Ll) {
  // P stride 136 = 8*17: rows 16B-aligned, odd-s -> even 8-phase bank spread
  __shared__ __align__(16) uint16_t P[64][136];
  __shared__ float smax[64][4];     // per-(row, col-group) wave max
  __shared__ float lsum[64][4];     // per-(row, col-group) final l partials
  __shared__ float alpha_s[64];     // per-row alpha (reused as mstat in epilogue)

  const int t    = threadIdx.x;
  const int w    = t >> 6;
  const int lane = t & 63;
  const int lm   = lane & 15;
  const int qd   = lane >> 4;
  const int wr   = w >> 2;   // phase-A row group (0/1): rows [32wr, 32wr+32)
  const int wc   = w & 3;    // phase-A col group (0..3): cols [32wc, 32wc+32)

  const int par  = blockIdx.x & 1;
  const int tt   = 127 - (blockIdx.x >> 1);   // longest tiles first
  const int row0 = tt * 64;
  const int jn   = tt / 2 + 1;                // # of 128-key tiles for this row tile

  const float c1 = 0.045084220027780106f;     // log2(e) / sqrt(1024)

  float m_run[2][4], l_run[2][4];
#pragma unroll
  for (int mt = 0; mt < 2; ++mt)
#pragma unroll
    for (int r = 0; r < 4; ++r) { m_run[mt][r] = -1e30f; l_run[mt][r] = 0.0f; }

  f32x4 o_acc[4][8] = {};  // [row-tile mt2][d-tile dt], rows mt2*16+qd*4+r, d w*128+dt*16+lm

  const uint16_t* qbase = Qb + (size_t)(row0 + wr * 32 + lm) * DIM;
  const uint16_t* vbase0 = Vt + (size_t)(w * 128 + lm) * SEQ;

#pragma unroll 1
  for (int jg = par; jg < jn; jg += 2) {
    // ---- Phase A: sacc[2][2] = Q K^T for this wave's 32x32 sub-tile ------
    f32x4 sacc[2][2] = {};
    const uint16_t* kbase = Kb + (size_t)(jg * 128 + wc * 32 + lm) * DIM;
#pragma unroll 2
    for (int c = 0; c < 16; ++c) {
      bf16x8 qf[2][2], kf[2][2];
#pragma unroll
      for (int mt = 0; mt < 2; ++mt)
#pragma unroll
        for (int kc = 0; kc < 2; ++kc)
          qf[mt][kc] = *(const bf16x8*)(qbase + (size_t)mt * 16 * DIM + c * 64 + kc * 32 + qd * 8);
#pragma unroll
      for (int nt = 0; nt < 2; ++nt)
#pragma unroll
        for (int kc = 0; kc < 2; ++kc)
          kf[nt][kc] = *(const bf16x8*)(kbase + (size_t)nt * 16 * DIM + c * 64 + kc * 32 + qd * 8);
#pragma unroll
      for (int kc = 0; kc < 2; ++kc)
#pragma unroll
        for (int mt = 0; mt < 2; ++mt)
#pragma unroll
          for (int nt = 0; nt < 2; ++nt)
            sacc[mt][nt] = MFMA16(qf[mt][kc], kf[nt][kc], sacc[mt][nt]);
    }

    // ---- causal mask (only the diagonal tile) + in-register row max ------
    const bool maskt = (jg == jn - 1);
    if (maskt) {
#pragma unroll
      for (int mt = 0; mt < 2; ++mt)
#pragma unroll
        for (int nt = 0; nt < 2; ++nt)
#pragma unroll
          for (int r = 0; r < 4; ++r) {
            int col = jg * 128 + wc * 32 + nt * 16 + lm;
            int row = row0 + wr * 32 + mt * 16 + qd * 4 + r;
            if (col > row) sacc[mt][nt][r] = -1e30f;
          }
    }
    float rm[2][4];
#pragma unroll
    for (int mt = 0; mt < 2; ++mt)
#pragma unroll
      for (int r = 0; r < 4; ++r) {
        float v = fmaxf(sacc[mt][0][r], sacc[mt][1][r]);
        v = fmaxf(v, __shfl_xor(v, 1));
        v = fmaxf(v, __shfl_xor(v, 2));
        v = fmaxf(v, __shfl_xor(v, 4));
        v = fmaxf(v, __shfl_xor(v, 8));
        rm[mt][r] = v;
      }
    if (lm == 0) {
#pragma unroll
      for (int mt = 0; mt < 2; ++mt)
#pragma unroll
        for (int r = 0; r < 4; ++r)
          smax[wr * 32 + mt * 16 + qd * 4 + r][wc] = rm[mt][r];
    }
    __syncthreads();

    // ---- softmax in registers; write P (bf16) to LDS ---------------------
    float alpha[2][4], mnew[2][4], psum[2][4];
#pragma unroll
    for (int mt = 0; mt < 2; ++mt)
#pragma unroll
      for (int r = 0; r < 4; ++r) {
        int rl = wr * 32 + mt * 16 + qd * 4 + r;
        float4 g = *(const float4*)&smax[rl][0];
        float gm = fmaxf(fmaxf(g.x, g.y), fmaxf(g.z, g.w));
        float mn = fmaxf(m_run[mt][r], gm);
        alpha[mt][r] = exp2f((m_run[mt][r] - mn) * c1);
        m_run[mt][r] = mn;
        mnew[mt][r] = mn;
        psum[mt][r] = 0.0f;
      }
#pragma unroll
    for (int mt = 0; mt < 2; ++mt)
#pragma unroll
      for (int nt = 0; nt < 2; ++nt)
#pragma unroll
      for (int r = 0; r < 4; ++r) {
        float p = exp2f((sacc[mt][nt][r] - mnew[mt][r]) * c1);
        psum[mt][r] += p;
        P[wr * 32 + mt * 16 + qd * 4 + r][wc * 32 + nt * 16 + lm] = f2bf(p);
      }
#pragma unroll
    for (int mt = 0; mt < 2; ++mt)
#pragma unroll
      for (int r = 0; r < 4; ++r) {
        float s = psum[mt][r];
        s += __shfl_xor(s, 1);
        s += __shfl_xor(s, 2);
        s += __shfl_xor(s, 4);
        s += __shfl_xor(s, 8);
        l_run[mt][r] = l_run[mt][r] * alpha[mt][r] + s;  // wave-local (32 cols)
      }
    if (wc == 0 && lm == 0) {
#pragma unroll
      for (int mt = 0; mt < 2; ++mt)
#pragma unroll
        for (int r = 0; r < 4; ++r)
          alpha_s[wr * 32 + mt * 16 + qd * 4 + r] = alpha[mt][r];
    }
    __syncthreads();

    // ---- Phase C: O = alpha*O + P @ V ------------------------------------
    float av[4][4];
#pragma unroll
    for (int mt2 = 0; mt2 < 4; ++mt2)
#pragma unroll
      for (int r = 0; r < 4; ++r)
        av[mt2][r] = alpha_s[mt2 * 16 + qd * 4 + r];
#pragma unroll
    for (int mt2 = 0; mt2 < 4; ++mt2)
#pragma unroll
      for (int dt = 0; dt < 8; ++dt)
#pragma unroll
        for (int r = 0; r < 4; ++r)
          o_acc[mt2][dt][r] *= av[mt2][r];

    const uint16_t* vb = vbase0 + (size_t)jg * 128;
#pragma unroll 2
    for (int kc = 0; kc < 4; ++kc) {
      bf16x8 pf[4];
#pragma unroll
      for (int mt2 = 0; mt2 < 4; ++mt2)
        pf[mt2] = *(const bf16x8*)(&P[mt2 * 16 + lm][kc * 32 + qd * 8]);
#pragma unroll
      for (int dt = 0; dt < 8; ++dt) {
        bf16x8 vf = *(const bf16x8*)(vb + (size_t)dt * 16 * SEQ + kc * 32 + qd * 8);
#pragma unroll
        for (int mt2 = 0; mt2 < 4; ++mt2)
          o_acc[mt2][dt] = MFMA16(pf[mt2], vf, o_acc[mt2][dt]);
      }
    }
    // next iter's smax writes happen after barrier1(i+1), which all waves reach
    // only after finishing this phase C -> no extra barrier needed here.
  }

  // ---- epilogue: cross-wave l reduction, write partial O + (m,l) ---------
  __syncthreads();  // protect alpha_s/lsum from in-flight phase-C readers
  if (lm == 0) {
#pragma unroll
    for (int mt = 0; mt < 2; ++mt)
#pragma unroll
      for (int r = 0; r < 4; ++r) {
        int rl = wr * 32 + mt * 16 + qd * 4 + r;
        lsum[rl][wc] = l_run[mt][r];
        if (wc == 0) alpha_s[rl] = m_run[mt][r];  // alpha_s reused as m-stat
      }
  }
  __syncthreads();
  if (t < 64) {
    Mm[par * SEQ + row0 + t] = alpha_s[t];
    Ll[par * SEQ + row0 + t] = lsum[t][0] + lsum[t][1] + lsum[t][2] + lsum[t][3];
  }
  uint16_t* Pp = par ? P1 : P0;
#pragma unroll
  for (int mt2 = 0; mt2 < 4; ++mt2)
#pragma unroll
    for (int dt = 0; dt < 8; ++dt)
#pragma unroll
      for (int r = 0; r < 4; ++r) {
        int row = row0 + mt2 * 16 + qd * 4 + r;
        int d   = w * 128 + dt * 16 + lm;
        Pp[(size_t)row * DIM + d] = f2bf(o_acc[mt2][dt][r]);
      }
}

// ------------------------------------------------------------ merge partials (known-good)
__global__ __launch_bounds__(256) void merge_kernel(const uint16_t* __restrict__ P0,
                                                    const uint16_t* __restrict__ P1,
                                                    const float* __restrict__ Mm,
                                                    const float* __restrict__ Ll,
                                                    float* __restrict__ out) {
  const int row = blockIdx.x;
  const int d0  = threadIdx.x * 4;
  const float c1 = 0.045084220027780106f;
  float m0 = Mm[row], m1 = Mm[SEQ + row];
  float l0 = Ll[row], l1 = Ll[SEQ + row];
  float m  = fmaxf(m0, m1);
  float a0 = exp2f((m0 - m) * c1);
  float a1 = exp2f((m1 - m) * c1);
  float inv = 1.0f / (a0 * l0 + a1 * l1);
  ushort4 p0 = *(const ushort4*)(P0 + (size_t)row * DIM + d0);
  ushort4 p1 = *(const ushort4*)(P1 + (size_t)row * DIM + d0);
  float4 o;
  o.x = (a0 * bf2f(p0.x) + a1 * bf2f(p1.x)) * inv;
  o.y = (a0 * bf2f(p0.y) + a1 * bf2f(p1.y)) * inv;
  o.z = (a0 * bf2f(p0.z) + a1 * bf2f(p1.z)) * inv;
  o.w = (a0 * bf2f(p0.w) + a1 * bf2f(p1.w)) * inv;
  *(float4*)(out + (size_t)row * DIM + d0) = o;
}

// ---------------------------------------------------------------- launch
extern "C" void kernel_launch(void* const* d_in, const int* in_sizes, int n_in,
                              void* d_out, int out_size, void* d_ws, size_t ws_size,
                              hipStream_t stream) {
  (void)in_sizes; (void)n_in; (void)out_size; (void)ws_size;
  const float* x  = (const float*)d_in[0];
  const float* wq = (const float*)d_in[1];
  const float* wk = (const float*)d_in[2];
  const float* wv = (const float*)d_in[3];
  float* out = (float*)d_out;

  char* ws = (char*)d_ws;
  uint16_t* Qb   = (uint16_t*)(ws);
  uint16_t* Kb   = (uint16_t*)(ws + 16777216);
  uint16_t* Vt   = (uint16_t*)(ws + 33554432);
  uint16_t* Vb   = (uint16_t*)(ws + 50331648);
  uint16_t* P0   = (uint16_t*)(ws + 50331648);   // aliases Vb (dead after transpose)
  uint16_t* xb   = (uint16_t*)(ws + 67108864);
  uint16_t* P1   = (uint16_t*)(ws + 67108864);   // aliases xb (dead after GEMM)
  uint16_t* wcat = (uint16_t*)(ws + 83886080);
  float*    Mm   = (float*)(ws + 83886080);      // aliases wcat (dead after GEMM)
  float*    Ll   = (float*)(ws + 83886080 + 65536);

  cast_f32_bf16<<<8192, 256, 0, stream>>>(x,  xb,                   SEQ * DIM);
  cast_f32_bf16<<<1024, 256, 0, stream>>>(wq, wcat,                 DIM * DIM);
  cast_f32_bf16<<<1024, 256, 0, stream>>>(wk, wcat + DIM * DIM,     DIM * DIM);
  cast_f32_bf16<<<1024, 256, 0, stream>>>(wv, wcat + 2 * DIM * DIM, DIM * DIM);

  qkv_gemm<<<dim3(24, 64), 256, 0, stream>>>(xb, wcat, Qb, Kb, Vb);
  transpose_v<<<dim3(SEQ / 64, DIM / 64), 256, 0, stream>>>(Vb, Vt);
  attn_kernel<<<256, 512, 0, stream>>>(Qb, Kb, Vt, P0, P1, Mm, Ll);
  merge_kernel<<<SEQ, 256, 0, stream>>>(P0, P1, Mm, Ll, out);
}

// Round 4
// 557.607 us; speedup vs baseline: 3.4990x; 2.5929x over previous
//
#include <hip/hip_runtime.h>
#include <stdint.h>
#include <stddef.h>

// S=8192, D=1024 causal attention + QKV proj.
// cast->bf16, fused QKV MFMA GEMM (writes Q/K in blocked MFMA-fragment layout),
// V transpose (writes blocked B-frag layout), flash attention (Br=32, Bc=256,
// 8 waves, pair-balanced grid + key-parity split-2, all operand loads
// lane-contiguous), merge kernel.

#define SEQ   8192
#define DIM   1024

typedef __bf16 bf16x8 __attribute__((ext_vector_type(8)));
typedef float  f32x4  __attribute__((ext_vector_type(4)));
typedef uint16_t u16x8 __attribute__((ext_vector_type(8)));

#define MFMA16(a, b, c) __builtin_amdgcn_mfma_f32_16x16x32_bf16((a), (b), (c), 0, 0, 0)

__device__ __forceinline__ uint16_t f2bf(float f) {
  uint32_t u = __builtin_bit_cast(uint32_t, f);
  return (uint16_t)((u + 0x7fffu + ((u >> 16) & 1u)) >> 16);
}
__device__ __forceinline__ float bf2f(uint16_t h) {
  uint32_t u = ((uint32_t)h) << 16;
  return __builtin_bit_cast(float, u);
}

typedef const __attribute__((address_space(1))) uint32_t* gas_t;
typedef __attribute__((address_space(3))) uint32_t* las_t;
__device__ __forceinline__ void async16(const void* g, void* l) {
  __builtin_amdgcn_global_load_lds((gas_t)g, (las_t)l, 16, 0, 0);
}

// Blocked fragment layouts (element offsets):
//  A-frag store for X[row][feat]:  ((row>>4)*32 + (feat>>5))*512 + ((feat>>3)&3)*16*8 + (row&15)*8 + (feat&7)
//  (i.e. [row16-tile][feat32-blk][lane=qd*16+lm][8]; lane qd=(feat>>3)&3, lm=row&15)
//  V B-frag store for V[key][d]:   ((d>>4)*256 + (key>>5))*512 + ((key>>3)&3)*16*8 + (d&15)*8 + (key&7)

// ---------------------------------------------------------------- cast kernel
__global__ __launch_bounds__(256) void cast_f32_bf16(const float* __restrict__ src,
                                                     uint16_t* __restrict__ dst, int n) {
  int i = (blockIdx.x * 256 + threadIdx.x) * 4;
  if (i + 3 < n) {
    float4 v = *(const float4*)(src + i);
    ushort4 o;
    o.x = f2bf(v.x); o.y = f2bf(v.y); o.z = f2bf(v.z); o.w = f2bf(v.w);
    *(ushort4*)(dst + i) = o;
  }
}

// ------------------------------------------------------------- QKV GEMM
// Q,K written in blocked A/B-frag layout; V row-major (transposed next).
__global__ __launch_bounds__(256) void qkv_gemm(const uint16_t* __restrict__ A,
                                                const uint16_t* __restrict__ B,
                                                uint16_t* __restrict__ Qblk,
                                                uint16_t* __restrict__ Kblk,
                                                uint16_t* __restrict__ Vb) {
  __shared__ __align__(16) uint16_t As[128][72];
  __shared__ __align__(16) uint16_t Bs[128][72];
  const int t    = threadIdx.x;
  const int w    = t >> 6;
  const int lane = t & 63;
  const int lm   = lane & 15;
  const int qd   = lane >> 4;
  const int wrow = (w >> 1) * 64;
  const int wcol = (w & 1) * 64;
  const int rowbase = blockIdx.y * 128;
  const int colbase = blockIdx.x * 128;

  f32x4 acc[4][4] = {};

  for (int kb = 0; kb < DIM; kb += 64) {
    __syncthreads();
#pragma unroll
    for (int rep = 0; rep < 4; ++rep) {
      int i = rep * 256 + t;
      int r = i >> 3, c8 = i & 7;
      *(uint4*)(&As[r][c8 * 8]) =
          *(const uint4*)(A + (size_t)(rowbase + r) * DIM + kb + c8 * 8);
    }
#pragma unroll
    for (int rep = 0; rep < 4; ++rep) {
      int i = rep * 256 + t;
      int r = i >> 3, c8 = i & 7;
      *(uint4*)(&Bs[r][c8 * 8]) =
          *(const uint4*)(B + (size_t)(colbase + r) * DIM + kb + c8 * 8);
    }
    __syncthreads();
#pragma unroll
    for (int kc = 0; kc < 2; ++kc) {
      bf16x8 af[4], bfr[4];
#pragma unroll
      for (int mt = 0; mt < 4; ++mt)
        af[mt] = *(const bf16x8*)(&As[wrow + mt * 16 + lm][kc * 32 + qd * 8]);
#pragma unroll
      for (int nt = 0; nt < 4; ++nt)
        bfr[nt] = *(const bf16x8*)(&Bs[wcol + nt * 16 + lm][kc * 32 + qd * 8]);
#pragma unroll
      for (int mt = 0; mt < 4; ++mt)
#pragma unroll
        for (int nt = 0; nt < 4; ++nt)
          acc[mt][nt] = MFMA16(af[mt], bfr[nt], acc[mt][nt]);
    }
  }

#pragma unroll
  for (int mt = 0; mt < 4; ++mt)
#pragma unroll
    for (int nt = 0; nt < 4; ++nt)
#pragma unroll
      for (int r = 0; r < 4; ++r) {
        int m = rowbase + wrow + mt * 16 + qd * 4 + r;
        int n = colbase + wcol + nt * 16 + lm;
        uint16_t v = f2bf(acc[mt][nt][r]);
        int nn = n & 1023;
        if (n < 2048) {
          size_t off = (((size_t)(m >> 4) * 32 + (nn >> 5)) * 64 +
                        ((nn >> 3) & 3) * 16 + (m & 15)) * 8 + (nn & 7);
          if (n < 1024) Qblk[off] = v; else Kblk[off] = v;
        } else {
          Vb[(size_t)m * DIM + nn] = v;
        }
      }
}

// ------------------------------------------------------------ V transpose
// Vb [8192,1024] row-major -> Vblk blocked B-frag layout.
__global__ __launch_bounds__(256) void transpose_v(const uint16_t* __restrict__ Vb,
                                                   uint16_t* __restrict__ Vblk) {
  __shared__ __align__(16) uint16_t tile[64][72];
  const int t  = threadIdx.x;
  const int mb = blockIdx.x * 64;   // key base
  const int db = blockIdx.y * 64;   // d base
#pragma unroll
  for (int rep = 0; rep < 2; ++rep) {
    int i = rep * 256 + t;
    int r = i >> 3, c = (i & 7) * 8;
    *(uint4*)(&tile[r][c]) = *(const uint4*)(Vb + (size_t)(mb + r) * DIM + db + c);
  }
  __syncthreads();
#pragma unroll
  for (int rep = 0; rep < 2; ++rep) {
    int i = rep * 256 + t;
    int d = i >> 3, mq = (i & 7) * 8;
    u16x8 v;
#pragma unroll
    for (int u = 0; u < 8; ++u) v[u] = tile[mq + u][d];
    int dg = db + d, kg = mb + mq;  // kg is 8-aligned
    size_t off = (((size_t)(dg >> 4) * 256 + (kg >> 5)) * 64 +
                  ((kg >> 3) & 3) * 16 + (dg & 15)) * 8;
    *(u16x8*)(Vblk + off) = v;
  }
}

// ------------------------------------------------------------ flash attention
// Br=32 rows, Bc=256 keys/iter, 8 waves (512 thr).
// grid=256: block b -> pair p=b>>1, par=b&1. Halves: tt=p then tt=255-p
// (tt in [0,256), row0=tt*32, jn=tt/8+1, jg=par,par+2,...).
// Phase A: wave w owns S cols [32w,32w+32); Q from LDS (blocked), K direct
// global (blocked) -- all loads lane-contiguous 1KB. Softmax in registers,
// cross-wave stats via smax/lsum. P stored blocked in LDS. Phase C: wave w
// owns d-slice [128w,128w+128); V direct global (blocked).
__global__ __launch_bounds__(512, 2) void attn_kernel(const uint16_t* __restrict__ Qblk,
                                                      const uint16_t* __restrict__ Kblk,
                                                      const uint16_t* __restrict__ Vblk,
                                                      uint16_t* __restrict__ P0,
                                                      uint16_t* __restrict__ P1,
                                                      float* __restrict__ Mm,
                                                      float* __restrict__ Ll) {
  __shared__ __align__(16) uint16_t Qs[32768];   // [m16(2)][d32(32)][lane(64)][8] = 64KB
  __shared__ __align__(16) uint16_t Pb[8192];    // [m16(2)][k32(8)][lane(64)][8] = 16KB
  __shared__ float smax[32][8];
  __shared__ float lsum[32][8];
  __shared__ float mrow[32];

  const int t    = threadIdx.x;
  const int w    = t >> 6;
  const int lane = t & 63;
  const int lm   = lane & 15;
  const int qd   = lane >> 4;
  const int par  = blockIdx.x & 1;
  const int p    = blockIdx.x >> 1;
  const float c1 = 0.045084220027780106f;  // log2(e)/sqrt(1024)

#pragma unroll 1
  for (int half = 0; half < 2; ++half) {
    const int tt   = half ? 255 - p : p;
    const int row0 = tt * 32;
    const int jn   = (tt >> 3) + 1;

    // ---- stage Q half-tile (64KB contiguous copy of Qblk) ----------------
    __syncthreads();  // previous half done with Qs
#pragma unroll
    for (int i = 0; i < 8; ++i)
      async16(Qblk + ((size_t)(tt * 64 + w * 8 + i)) * 512 + lane * 8,
              Qs + (w * 8 + i) * 512);
    __syncthreads();  // drain DMA

    float m_run[2][4], l_run[2][4];
#pragma unroll
    for (int mt = 0; mt < 2; ++mt)
#pragma unroll
      for (int r = 0; r < 4; ++r) { m_run[mt][r] = -1e30f; l_run[mt][r] = 0.0f; }
    f32x4 o_acc[2][8] = {};

#pragma unroll 1
    for (int jg = par; jg < jn; jg += 2) {
      // ---- Phase A: sacc = Q K^T (32 rows x 32 cols this wave) -----------
      f32x4 sacc[2][2] = {};
      const uint16_t* kbp = Kblk + ((size_t)(jg * 16 + w * 2) * 32) * 512 + lane * 8;
      const uint16_t* qsp = Qs + lane * 8;
#pragma unroll 4
      for (int kb = 0; kb < 32; ++kb) {
        bf16x8 qf0 = *(const bf16x8*)(qsp + kb * 512);
        bf16x8 qf1 = *(const bf16x8*)(qsp + (32 + kb) * 512);
        bf16x8 kf0 = *(const bf16x8*)(kbp + (size_t)kb * 512);
        bf16x8 kf1 = *(const bf16x8*)(kbp + (size_t)(32 + kb) * 512);
        sacc[0][0] = MFMA16(qf0, kf0, sacc[0][0]);
        sacc[1][0] = MFMA16(qf1, kf0, sacc[1][0]);
        sacc[0][1] = MFMA16(qf0, kf1, sacc[0][1]);
        sacc[1][1] = MFMA16(qf1, kf1, sacc[1][1]);
      }

      // ---- causal mask (last tile only) ----------------------------------
      if (jg == jn - 1) {
#pragma unroll
        for (int mt = 0; mt < 2; ++mt)
#pragma unroll
          for (int nt = 0; nt < 2; ++nt)
#pragma unroll
            for (int r = 0; r < 4; ++r) {
              int col = jg * 256 + w * 32 + nt * 16 + lm;
              int row = row0 + mt * 16 + qd * 4 + r;
              if (col > row) sacc[mt][nt][r] = -1e30f;
            }
      }

      // ---- wave-local row max -> smax ------------------------------------
#pragma unroll
      for (int mt = 0; mt < 2; ++mt)
#pragma unroll
        for (int r = 0; r < 4; ++r) {
          float v = fmaxf(sacc[mt][0][r], sacc[mt][1][r]);
          v = fmaxf(v, __shfl_xor(v, 1));
          v = fmaxf(v, __shfl_xor(v, 2));
          v = fmaxf(v, __shfl_xor(v, 4));
          v = fmaxf(v, __shfl_xor(v, 8));
          if (lm == 0) smax[mt * 16 + qd * 4 + r][w] = v;
        }
      __syncthreads();

      // ---- softmax in registers; P (blocked) to LDS ----------------------
      float alpha[2][4], psum[2][4];
#pragma unroll
      for (int mt = 0; mt < 2; ++mt)
#pragma unroll
        for (int r = 0; r < 4; ++r) {
          int rl = mt * 16 + qd * 4 + r;
          float4 g0 = *(const float4*)&smax[rl][0];
          float4 g1 = *(const float4*)&smax[rl][4];
          float gm = fmaxf(fmaxf(fmaxf(g0.x, g0.y), fmaxf(g0.z, g0.w)),
                           fmaxf(fmaxf(g1.x, g1.y), fmaxf(g1.z, g1.w)));
          float mn = fmaxf(m_run[mt][r], gm);
          alpha[mt][r] = exp2f((m_run[mt][r] - mn) * c1);
          m_run[mt][r] = mn;
          psum[mt][r] = 0.0f;
        }
#pragma unroll
      for (int mt = 0; mt < 2; ++mt)
#pragma unroll
        for (int nt = 0; nt < 2; ++nt)
#pragma unroll
          for (int r = 0; r < 4; ++r) {
            float pv = exp2f((sacc[mt][nt][r] - m_run[mt][r]) * c1);
            psum[mt][r] += pv;
            Pb[((mt * 8 + w) * 64 + (nt * 2 + (lm >> 3)) * 16 + qd * 4 + r) * 8 + (lm & 7)] =
                f2bf(pv);
          }
#pragma unroll
      for (int mt = 0; mt < 2; ++mt)
#pragma unroll
        for (int r = 0; r < 4; ++r) {
          float s2 = psum[mt][r];
          s2 += __shfl_xor(s2, 1);
          s2 += __shfl_xor(s2, 2);
          s2 += __shfl_xor(s2, 4);
          s2 += __shfl_xor(s2, 8);
          l_run[mt][r] = l_run[mt][r] * alpha[mt][r] + s2;
        }
      __syncthreads();  // Pb ready

      // ---- Phase C: O = alpha*O + P @ V ----------------------------------
#pragma unroll
      for (int mt = 0; mt < 2; ++mt)
#pragma unroll
        for (int dt = 0; dt < 8; ++dt)
#pragma unroll
          for (int r = 0; r < 4; ++r)
            o_acc[mt][dt][r] *= alpha[mt][r];

      const uint16_t* vbp = Vblk + ((size_t)(w * 8) * 256 + jg * 8) * 512 + lane * 8;
#pragma unroll 2
      for (int kc = 0; kc < 8; ++kc) {
        bf16x8 pf0 = *(const bf16x8*)(Pb + (kc * 64 + lane) * 8);
        bf16x8 pf1 = *(const bf16x8*)(Pb + ((8 + kc) * 64 + lane) * 8);
#pragma unroll
        for (int dt = 0; dt < 8; ++dt) {
          bf16x8 vf = *(const bf16x8*)(vbp + ((size_t)dt * 256 + kc) * 512);
          o_acc[0][dt] = MFMA16(pf0, vf, o_acc[0][dt]);
          o_acc[1][dt] = MFMA16(pf1, vf, o_acc[1][dt]);
        }
      }
      // next iter's Pb writes are gated by the smax barrier after its phase A
    }

    // ---- epilogue: stats + unnormalized partial O ------------------------
    if (lm == 0) {
#pragma unroll
      for (int mt = 0; mt < 2; ++mt)
#pragma unroll
        for (int r = 0; r < 4; ++r) {
          int rl = mt * 16 + qd * 4 + r;
          lsum[rl][w] = l_run[mt][r];
          if (w == 0) mrow[rl] = m_run[mt][r];
        }
    }
    __syncthreads();
    if (t < 32) {
      float4 a0 = *(const float4*)&lsum[t][0];
      float4 a1 = *(const float4*)&lsum[t][4];
      Mm[par * SEQ + row0 + t] = mrow[t];
      Ll[par * SEQ + row0 + t] = (a0.x + a0.y + a0.z + a0.w) + (a1.x + a1.y + a1.z + a1.w);
    }
    uint16_t* Pp = par ? P1 : P0;
#pragma unroll
    for (int mt = 0; mt < 2; ++mt)
#pragma unroll
      for (int dt = 0; dt < 8; ++dt)
#pragma unroll
        for (int r = 0; r < 4; ++r) {
          int row = row0 + mt * 16 + qd * 4 + r;
          int d   = w * 128 + dt * 16 + lm;
          Pp[(size_t)row * DIM + d] = f2bf(o_acc[mt][dt][r]);
        }
  }
}

// ------------------------------------------------------------ merge partials
__global__ __launch_bounds__(256) void merge_kernel(const uint16_t* __restrict__ P0,
                                                    const uint16_t* __restrict__ P1,
                                                    const float* __restrict__ Mm,
                                                    const float* __restrict__ Ll,
                                                    float* __restrict__ out) {
  const int row = blockIdx.x;
  const int d0  = threadIdx.x * 4;
  const float c1 = 0.045084220027780106f;
  float m0 = Mm[row], m1 = Mm[SEQ + row];
  float l0 = Ll[row], l1 = Ll[SEQ + row];
  float m  = fmaxf(m0, m1);
  float a0 = exp2f((m0 - m) * c1);
  float a1 = exp2f((m1 - m) * c1);
  float inv = 1.0f / (a0 * l0 + a1 * l1);
  ushort4 p0 = *(const ushort4*)(P0 + (size_t)row * DIM + d0);
  ushort4 p1 = *(const ushort4*)(P1 + (size_t)row * DIM + d0);
  float4 o;
  o.x = (a0 * bf2f(p0.x) + a1 * bf2f(p1.x)) * inv;
  o.y = (a0 * bf2f(p0.y) + a1 * bf2f(p1.y)) * inv;
  o.z = (a0 * bf2f(p0.z) + a1 * bf2f(p1.z)) * inv;
  o.w = (a0 * bf2f(p0.w) + a1 * bf2f(p1.w)) * inv;
  *(float4*)(out + (size_t)row * DIM + d0) = o;
}

// ---------------------------------------------------------------- launch
extern "C" void kernel_launch(void* const* d_in, const int* in_sizes, int n_in,
                              void* d_out, int out_size, void* d_ws, size_t ws_size,
                              hipStream_t stream) {
  (void)in_sizes; (void)n_in; (void)out_size; (void)ws_size;
  const float* x  = (const float*)d_in[0];
  const float* wq = (const float*)d_in[1];
  const float* wk = (const float*)d_in[2];
  const float* wv = (const float*)d_in[3];
  float* out = (float*)d_out;

  char* ws = (char*)d_ws;
  uint16_t* Qblk = (uint16_t*)(ws);                  // 16MB blocked
  uint16_t* Kblk = (uint16_t*)(ws + 16777216);       // 16MB blocked
  uint16_t* Vblk = (uint16_t*)(ws + 33554432);       // 16MB blocked
  uint16_t* Vb   = (uint16_t*)(ws + 50331648);       // 16MB row-major V
  uint16_t* P0   = (uint16_t*)(ws + 50331648);       // aliases Vb (dead after transpose)
  uint16_t* xb   = (uint16_t*)(ws + 67108864);       // 16MB
  uint16_t* P1   = (uint16_t*)(ws + 67108864);       // aliases xb (dead after GEMM)
  uint16_t* wcat = (uint16_t*)(ws + 83886080);       // 6MB
  float*    Mm   = (float*)(ws + 83886080);          // aliases wcat (dead after GEMM)
  float*    Ll   = (float*)(ws + 83886080 + 65536);

  cast_f32_bf16<<<8192, 256, 0, stream>>>(x,  xb,                   SEQ * DIM);
  cast_f32_bf16<<<1024, 256, 0, stream>>>(wq, wcat,                 DIM * DIM);
  cast_f32_bf16<<<1024, 256, 0, stream>>>(wk, wcat + DIM * DIM,     DIM * DIM);
  cast_f32_bf16<<<1024, 256, 0, stream>>>(wv, wcat + 2 * DIM * DIM, DIM * DIM);

  qkv_gemm<<<dim3(24, 64), 256, 0, stream>>>(xb, wcat, Qblk, Kblk, Vb);
  transpose_v<<<dim3(SEQ / 64, DIM / 64), 256, 0, stream>>>(Vb, Vblk);
  attn_kernel<<<256, 512, 0, stream>>>(Qblk, Kblk, Vblk, P0, P1, Mm, Ll);
  merge_kernel<<<SEQ, 256, 0, stream>>>(P0, P1, Mm, Ll, out);
}